// Round 13
// baseline (96.060 us; speedup 1.0000x reference)
//
#include <hip/hip_runtime.h>
#include <hip/hip_bf16.h>
#include <math.h>

#define S_LEN 2048
#define C_DIM 512
#define NH 16
#define HD 32
#define PLANE_U (NH * S_LEN * HD)   // 1,048,576 ushorts = 2MB per plane

typedef __attribute__((ext_vector_type(8)))  short bf16x8;
typedef __attribute__((ext_vector_type(8)))  unsigned short u16x8;
typedef __attribute__((ext_vector_type(4)))  float f32x4;
typedef __attribute__((ext_vector_type(16))) float f32x16;
typedef __attribute__((ext_vector_type(4)))  unsigned int u32x4;

// pack 2 floats -> 2 bf16 in one dword via v_cvt_pk_bf16_f32 (RNE); a = low
__device__ __forceinline__ unsigned int pk_bf16(float a, float b) {
    float2 f; f.x = a; f.y = b;
    __hip_bfloat162 t = __float22bfloat162_rn(f);
    return *reinterpret_cast<unsigned int*>(&t);
}

// ---------------- projection: complex GEMM via bf16 MFMA ------------------
// A-operand (16 wave-private rows) is loaded DIRECTLY from global and
// converted in-register (no LDS); only the shared B tile is staged in LDS.
// z<2 (q,k): hi/lo split (12 mfma/tile-chunk), D = W·X^T -> [h][s][d]; the Q
//            plane is PRE-SCALED by 1/sqrt(32) (|c*s| = c*|s|, c>0).
// z==2 (v):  hi-only RNE (4 mfma/tile-chunk, err ~0.006), D = X·W^T -> V^T
//            plane [h][d][s], natural key order (32x32x16 PV A-operand).
#define PROW 40   // padded LDS row stride in ushorts (80B, 16B-aligned)

__global__ __launch_bounds__(256)
void proj_mfma(const float* __restrict__ Q, const float* __restrict__ V,
               const float* __restrict__ K,
               const float* __restrict__ Wq, const float* __restrict__ bq,
               const float* __restrict__ Wk, const float* __restrict__ bk,
               const float* __restrict__ Wv, const float* __restrict__ bv,
               unsigned short* __restrict__ ws)
{
    const int z = blockIdx.z;
    const float *X, *W, *b;
    if (z == 0)      { X = Q; W = Wq; b = bq; }
    else if (z == 1) { X = K; W = Wk; b = bk; }
    else             { X = V; W = Wv; b = bv; }
    const bool full = (z < 2);

    const int s0 = blockIdx.x * 64;
    const int o0 = blockIdx.y * 64;

    const float2 *Asrc, *Bsrc; int arow0, brow0;
    if (full) { Asrc = (const float2*)W; arow0 = o0; Bsrc = (const float2*)X; brow0 = s0; }
    else      { Asrc = (const float2*)X; arow0 = s0; Bsrc = (const float2*)W; brow0 = o0; }

    __shared__ __align__(16) unsigned short LBrh[64*PROW], LBrl[64*PROW];
    __shared__ __align__(16) unsigned short LBih[64*PROW], LBil[64*PROW];

    const int t    = threadIdx.x;
    const int wave = t >> 6;
    const int lr   = t & 15;
    const int g    = (t & 63) >> 4;
    const int srow = t >> 2;        // B staging row 0..63
    const int sk8  = (t & 3) * 8;   // B staging k chunk (8 complex)

    const f32x4 zf = {0.f,0.f,0.f,0.f};
    f32x4 accR[4], accI[4];
    #pragma unroll
    for (int i = 0; i < 4; ++i) { accR[i] = zf; accI[i] = zf; }

    // per-lane A row (wave-private) — direct global loads each k-step
    const float4* Arow4 = (const float4*)(Asrc + (size_t)(arow0 + wave*16 + lr)*C_DIM);

    for (int k0 = 0; k0 < C_DIM; k0 += 32) {
        // issue A-fragment global load early (overlaps barrier + B staging)
        const float4* a4 = Arow4 + ((k0 + g*8) >> 1);   // 8 complex = 4 float4
        float4 A0 = a4[0], A1 = a4[1], A2 = a4[2], A3 = a4[3];

        __syncthreads();   // previous B tile fully consumed
        // ---- stage B tile (shared across waves) ----
        {
            const float4* s4 = (const float4*)(Bsrc + (size_t)(brow0 + srow)*C_DIM + k0 + sk8);
            float4 f0 = s4[0], f1 = s4[1], f2v = s4[2], f3 = s4[3];
            float re[8] = {f0.x,f0.z,f1.x,f1.z,f2v.x,f2v.z,f3.x,f3.z};
            float im[8] = {f0.y,f0.w,f1.y,f1.w,f2v.y,f2v.w,f3.y,f3.w};
            u32x4 rh, ih, rl, il;
            if (full) {
                #pragma unroll
                for (int p2 = 0; p2 < 4; ++p2) {
                    float r0f = re[2*p2], r1f = re[2*p2+1];
                    float i0f = im[2*p2], i1f = im[2*p2+1];
                    unsigned int br0 = __float_as_uint(r0f), br1 = __float_as_uint(r1f);
                    unsigned int bi0 = __float_as_uint(i0f), bi1 = __float_as_uint(i1f);
                    rh[p2] = __builtin_amdgcn_perm(br1, br0, 0x07060302u);  // [hi16(r1):hi16(r0)]
                    ih[p2] = __builtin_amdgcn_perm(bi1, bi0, 0x07060302u);
                    rl[p2] = pk_bf16(r0f - __uint_as_float(br0 & 0xFFFF0000u),
                                     r1f - __uint_as_float(br1 & 0xFFFF0000u));
                    il[p2] = pk_bf16(i0f - __uint_as_float(bi0 & 0xFFFF0000u),
                                     i1f - __uint_as_float(bi1 & 0xFFFF0000u));
                }
            } else {
                #pragma unroll
                for (int p2 = 0; p2 < 4; ++p2) {
                    rh[p2] = pk_bf16(re[2*p2], re[2*p2+1]);
                    ih[p2] = pk_bf16(im[2*p2], im[2*p2+1]);
                }
            }
            int wb = srow*PROW + sk8;
            *(u32x4*)&LBrh[wb] = rh; *(u32x4*)&LBih[wb] = ih;
            if (full) { *(u32x4*)&LBrl[wb] = rl; *(u32x4*)&LBil[wb] = il; }
        }

        // ---- convert A fragment in-register (while B stores land) ----
        bf16x8 aRH, aIH, aRL, aIL;
        {
            float re[8] = {A0.x,A0.z,A1.x,A1.z,A2.x,A2.z,A3.x,A3.z};
            float im[8] = {A0.y,A0.w,A1.y,A1.w,A2.y,A2.w,A3.y,A3.w};
            u32x4 rh, ih, rl, il;
            if (full) {
                #pragma unroll
                for (int p2 = 0; p2 < 4; ++p2) {
                    float r0f = re[2*p2], r1f = re[2*p2+1];
                    float i0f = im[2*p2], i1f = im[2*p2+1];
                    unsigned int br0 = __float_as_uint(r0f), br1 = __float_as_uint(r1f);
                    unsigned int bi0 = __float_as_uint(i0f), bi1 = __float_as_uint(i1f);
                    rh[p2] = __builtin_amdgcn_perm(br1, br0, 0x07060302u);
                    ih[p2] = __builtin_amdgcn_perm(bi1, bi0, 0x07060302u);
                    rl[p2] = pk_bf16(r0f - __uint_as_float(br0 & 0xFFFF0000u),
                                     r1f - __uint_as_float(br1 & 0xFFFF0000u));
                    il[p2] = pk_bf16(i0f - __uint_as_float(bi0 & 0xFFFF0000u),
                                     i1f - __uint_as_float(bi1 & 0xFFFF0000u));
                }
                aRL = *(bf16x8*)&rl; aIL = *(bf16x8*)&il;
            } else {
                #pragma unroll
                for (int p2 = 0; p2 < 4; ++p2) {
                    rh[p2] = pk_bf16(re[2*p2], re[2*p2+1]);
                    ih[p2] = pk_bf16(im[2*p2], im[2*p2+1]);
                }
            }
            aRH = *(bf16x8*)&rh; aIH = *(bf16x8*)&ih;
        }
        bf16x8 aIHn;
        #pragma unroll
        for (int j = 0; j < 8; ++j) aIHn[j] = aIH[j] ^ (short)0x8000;

        __syncthreads();   // B tile visible

        if (full) {
            bf16x8 aILn;
            #pragma unroll
            for (int j = 0; j < 8; ++j) aILn[j] = aIL[j] ^ (short)0x8000;

            #pragma unroll
            for (int tile = 0; tile < 4; ++tile) {
                const int bb = (tile*16 + lr)*PROW + g*8;
                bf16x8 bRH = *(const bf16x8*)&LBrh[bb];
                bf16x8 bRL = *(const bf16x8*)&LBrl[bb];
                bf16x8 bIH = *(const bf16x8*)&LBih[bb];
                bf16x8 bIL = *(const bf16x8*)&LBil[bb];
                accR[tile] = __builtin_amdgcn_mfma_f32_16x16x32_bf16(aRH,  bRH, accR[tile], 0,0,0);
                accR[tile] = __builtin_amdgcn_mfma_f32_16x16x32_bf16(aRL,  bRH, accR[tile], 0,0,0);
                accR[tile] = __builtin_amdgcn_mfma_f32_16x16x32_bf16(aRH,  bRL, accR[tile], 0,0,0);
                accR[tile] = __builtin_amdgcn_mfma_f32_16x16x32_bf16(aIHn, bIH, accR[tile], 0,0,0);
                accR[tile] = __builtin_amdgcn_mfma_f32_16x16x32_bf16(aILn, bIH, accR[tile], 0,0,0);
                accR[tile] = __builtin_amdgcn_mfma_f32_16x16x32_bf16(aIHn, bIL, accR[tile], 0,0,0);
                accI[tile] = __builtin_amdgcn_mfma_f32_16x16x32_bf16(aRH,  bIH, accI[tile], 0,0,0);
                accI[tile] = __builtin_amdgcn_mfma_f32_16x16x32_bf16(aRL,  bIH, accI[tile], 0,0,0);
                accI[tile] = __builtin_amdgcn_mfma_f32_16x16x32_bf16(aRH,  bIL, accI[tile], 0,0,0);
                accI[tile] = __builtin_amdgcn_mfma_f32_16x16x32_bf16(aIH,  bRH, accI[tile], 0,0,0);
                accI[tile] = __builtin_amdgcn_mfma_f32_16x16x32_bf16(aIL,  bRH, accI[tile], 0,0,0);
                accI[tile] = __builtin_amdgcn_mfma_f32_16x16x32_bf16(aIH,  bRL, accI[tile], 0,0,0);
            }
        } else {
            #pragma unroll
            for (int tile = 0; tile < 4; ++tile) {
                const int bb = (tile*16 + lr)*PROW + g*8;
                bf16x8 bRH = *(const bf16x8*)&LBrh[bb];
                bf16x8 bIH = *(const bf16x8*)&LBih[bb];
                accR[tile] = __builtin_amdgcn_mfma_f32_16x16x32_bf16(aRH,  bRH, accR[tile], 0,0,0);
                accR[tile] = __builtin_amdgcn_mfma_f32_16x16x32_bf16(aIHn, bIH, accR[tile], 0,0,0);
                accI[tile] = __builtin_amdgcn_mfma_f32_16x16x32_bf16(aRH,  bIH, accI[tile], 0,0,0);
                accI[tile] = __builtin_amdgcn_mfma_f32_16x16x32_bf16(aIH,  bRH, accI[tile], 0,0,0);
            }
        }
    }

    // ---- epilogue ----
    const float2* b2 = (const float2*)b;
    if (full) {
        // Q plane pre-scaled by 1/sqrt(32) (fold softmax scale into scores)
        const float osc = (z == 0) ? 0.17677669529663687f : 1.0f;
        unsigned short* pr = ws + (z == 0 ? 0 : 2) * (size_t)PLANE_U;
        unsigned short* pi = pr + PLANE_U;
        const int obase = o0 + wave*16 + g*4;
        const int h = obase >> 5, d0 = obase & 31;
        float bR[4], bI[4];
        #pragma unroll
        for (int r = 0; r < 4; ++r) { float2 bb = b2[obase + r]; bR[r] = bb.x; bI[r] = bb.y; }
        #pragma unroll
        for (int tile = 0; tile < 4; ++tile) {
            int s = s0 + tile*16 + lr;
            size_t idx = ((size_t)h*S_LEN + s)*HD + d0;
            uint2 pkR, pkI;
            pkR.x = pk_bf16((accR[tile][0]+bR[0])*osc, (accR[tile][1]+bR[1])*osc);
            pkR.y = pk_bf16((accR[tile][2]+bR[2])*osc, (accR[tile][3]+bR[3])*osc);
            pkI.x = pk_bf16((accI[tile][0]+bI[0])*osc, (accI[tile][1]+bI[1])*osc);
            pkI.y = pk_bf16((accI[tile][2]+bI[2])*osc, (accI[tile][3]+bI[3])*osc);
            *(uint2*)&pr[idx] = pkR;
            *(uint2*)&pi[idx] = pkI;
        }
    } else {
        unsigned short* tr = ws + 4 * (size_t)PLANE_U;
        unsigned short* ti = tr + PLANE_U;
        const int sbase = s0 + wave*16 + g*4;    // natural key order
        #pragma unroll
        for (int tile = 0; tile < 4; ++tile) {
            int o = o0 + tile*16 + lr;
            int h = o >> 5, d = o & 31;
            float2 bb = b2[o];
            size_t idx = ((size_t)h*HD + d)*S_LEN + sbase;
            uint2 pkR, pkI;
            pkR.x = pk_bf16(accR[tile][0]+bb.x, accR[tile][1]+bb.x);
            pkR.y = pk_bf16(accR[tile][2]+bb.x, accR[tile][3]+bb.x);
            pkI.x = pk_bf16(accI[tile][0]+bb.y, accI[tile][1]+bb.y);
            pkI.y = pk_bf16(accI[tile][2]+bb.y, accI[tile][3]+bb.y);
            *(uint2*)&tr[idx] = pkR;
            *(uint2*)&ti[idx] = pkI;
        }
    }
}

// ---------------- MFMA flash attention: 32x32x16, split-K 4 --------------
// One 32x32x16 covers all 32 q-rows of the block. QK^T: S = mfma(K, Q) with
// the KEY->A-row permutation kappa(row) chosen so D-reg r of lane-half b
// holds key {8b+r} (r<8) / {16+8b+r-8} (r>=8) -> P packs DIRECTLY into the
// PV B-fragment (8 cvt_pk, no cross-lane, no LDS). PV: O^T = mfma(V^T, P)
// with V^T natural [h][d][s]. k-loop unrolled x2: two independent 32-key
// groups' QK/softmax/PV interleave to hide the serial chain. 4 waves/block
// (256 thr) x split-K 4. Partials purely additive (no max tracking;
// |s| <= ~15). Combine: two-stage into [2][32][33] float2 (conflict-free).
#define RROW 33

__global__ __launch_bounds__(256, 4)
void attn_mfma(const unsigned short* __restrict__ ws, float* __restrict__ out)
{
    const int bid   = blockIdx.x;       // 64 q-blocks x 16 heads
    const int h     = bid & (NH - 1);   // bid%8 = head%8 -> per-XCD KV locality
    const int qblk  = bid >> 4;         // 0..63
    const int wave  = threadIdx.x >> 6; // 0..3 -> k-range owner
    const int l     = threadIdx.x & 63;
    const int q     = l & 31;           // q-col AND V^T d-row AND PV q-col
    const int b     = l >> 5;           // lane half

    const unsigned short* qr  = ws + 0*(size_t)PLANE_U + (size_t)h*S_LEN*HD;
    const unsigned short* qi  = ws + 1*(size_t)PLANE_U + (size_t)h*S_LEN*HD;
    const unsigned short* kr  = ws + 2*(size_t)PLANE_U + (size_t)h*S_LEN*HD;
    const unsigned short* ki  = ws + 3*(size_t)PLANE_U + (size_t)h*S_LEN*HD;
    const unsigned short* vtr = ws + 4*(size_t)PLANE_U + (size_t)h*HD*S_LEN;
    const unsigned short* vti = ws + 5*(size_t)PLANE_U + (size_t)h*HD*S_LEN;

    const int q0 = qblk * 32;

    // key -> A-row permutation (see header comment); fixed per lane
    const int row   = q;
    const int kappa = (row & 16) + (((row >> 2) & 1) << 3) + (row & 3)
                    + (((row >> 3) & 1) << 2);

    // Q fragments (B-operand): lane supplies Q[q][d = b*8+j] (lo) / +16 (hi)
    bf16x8 bQr_lo = *(const bf16x8*)&qr[(size_t)(q0 + q)*HD + b*8];
    bf16x8 bQr_hi = *(const bf16x8*)&qr[(size_t)(q0 + q)*HD + 16 + b*8];
    bf16x8 bQi_lo = *(const bf16x8*)&qi[(size_t)(q0 + q)*HD + b*8];
    bf16x8 bQi_hi = *(const bf16x8*)&qi[(size_t)(q0 + q)*HD + 16 + b*8];

    // LDS only for the end-of-kernel two-stage combine: [2][32][33] float2
    __shared__ __align__(16) float2 red[2*32*RROW];

    f32x16 accR, accI;
    #pragma unroll
    for (int r = 0; r < 16; ++r) { accR[r] = 0.f; accI[r] = 0.f; }
    float lsum = 0.f;

    const f32x16 z16 = {0,0,0,0,0,0,0,0,0,0,0,0,0,0,0,0};
    const int kbeg = wave * 512;
    #pragma unroll 2
    for (int k0 = kbeg; k0 < kbeg + 512; k0 += 32) {
        // ---- K fragments: A[row][k] with permuted key rows ----
        const size_t krow = (size_t)(k0 + kappa)*HD + b*8;
        bf16x8 aKr_lo = *(const bf16x8*)&kr[krow];
        bf16x8 aKr_hi = *(const bf16x8*)&kr[krow + 16];
        bf16x8 aKi_lo = *(const bf16x8*)&ki[krow];
        bf16x8 aKi_hi = *(const bf16x8*)&ki[krow + 16];
        bf16x8 aKin_lo, aKin_hi;    // -Ki (transient)
        #pragma unroll
        for (int j = 0; j < 4; ++j) {
            ((unsigned int*)&aKin_lo)[j] = ((const unsigned int*)&aKi_lo)[j] ^ 0x80008000u;
            ((unsigned int*)&aKin_hi)[j] = ((const unsigned int*)&aKi_hi)[j] ^ 0x80008000u;
        }
        // ---- QK^T: 8 mfma, two independent 4-chains ----
        f32x16 sR = __builtin_amdgcn_mfma_f32_32x32x16_bf16(aKr_lo,  bQr_lo, z16, 0, 0, 0);
        f32x16 sI = __builtin_amdgcn_mfma_f32_32x32x16_bf16(aKin_lo, bQr_lo, z16, 0, 0, 0);
        sR = __builtin_amdgcn_mfma_f32_32x32x16_bf16(aKr_hi,  bQr_hi, sR, 0, 0, 0);
        sI = __builtin_amdgcn_mfma_f32_32x32x16_bf16(aKin_hi, bQr_hi, sI, 0, 0, 0);
        sR = __builtin_amdgcn_mfma_f32_32x32x16_bf16(aKi_lo,  bQi_lo, sR, 0, 0, 0);
        sI = __builtin_amdgcn_mfma_f32_32x32x16_bf16(aKr_lo,  bQi_lo, sI, 0, 0, 0);
        sR = __builtin_amdgcn_mfma_f32_32x32x16_bf16(aKi_hi,  bQi_hi, sR, 0, 0, 0);
        sI = __builtin_amdgcn_mfma_f32_32x32x16_bf16(aKr_hi,  bQi_hi, sI, 0, 0, 0);
        // ---- softmax: p[r] lands exactly in PV B-frag order ----
        bf16x8 bP1, bP2;
        unsigned int* p1 = (unsigned int*)&bP1;
        unsigned int* p2 = (unsigned int*)&bP2;
        #pragma unroll
        for (int r2 = 0; r2 < 8; ++r2) {
            int r = 2*r2;
            float v0 = __expf(__builtin_amdgcn_sqrtf(fmaf(sR[r],   sR[r],   sI[r]*sI[r])));
            float v1 = __expf(__builtin_amdgcn_sqrtf(fmaf(sR[r+1], sR[r+1], sI[r+1]*sI[r+1])));
            lsum += v0 + v1;
            if (r2 < 4) p1[r2]     = pk_bf16(v0, v1);
            else        p2[r2 - 4] = pk_bf16(v0, v1);
        }
        // ---- PV: A = V^T (natural, 16B loads), B = P in-register ----
        const size_t vrow = (size_t)q*S_LEN + k0 + b*8;
        bf16x8 aVr_lo = *(const bf16x8*)&vtr[vrow];
        bf16x8 aVr_hi = *(const bf16x8*)&vtr[vrow + 16];
        bf16x8 aVi_lo = *(const bf16x8*)&vti[vrow];
        bf16x8 aVi_hi = *(const bf16x8*)&vti[vrow + 16];
        accR = __builtin_amdgcn_mfma_f32_32x32x16_bf16(aVr_lo, bP1, accR, 0, 0, 0);
        accI = __builtin_amdgcn_mfma_f32_32x32x16_bf16(aVi_lo, bP1, accI, 0, 0, 0);
        accR = __builtin_amdgcn_mfma_f32_32x32x16_bf16(aVr_hi, bP2, accR, 0, 0, 0);
        accI = __builtin_amdgcn_mfma_f32_32x32x16_bf16(aVi_hi, bP2, accI, 0, 0, 0);
    }

    // lane pair (l, l^32) handled complementary key halves of the same q
    lsum += __shfl_xor(lsum, 32);

    // ---- two-stage combine: waves 0,1 write; 2,3 add; all reduce ----
    const int rrow = ((wave & 1) * 32 + q) * RROW;
    __syncthreads();
    if (wave < 2) {
        #pragma unroll
        for (int r = 0; r < 16; ++r) {
            int d = (r & 3) + 8*(r >> 2) + 4*b;   // PV D row = output d
            red[rrow + d] = make_float2(accR[r], accI[r]);
        }
        if (b == 0) red[rrow + 32].x = lsum;
    }
    __syncthreads();
    if (wave >= 2) {
        #pragma unroll
        for (int r = 0; r < 16; ++r) {
            int d = (r & 3) + 8*(r >> 2) + 4*b;
            float2 v = red[rrow + d];
            v.x += accR[r]; v.y += accI[r];
            red[rrow + d] = v;
        }
        if (b == 0) red[rrow + 32].x += lsum;
    }
    __syncthreads();

    // thread i: q-row = i>>3, d = (i&7)*4 .. +3 ; sum 2 stage-partials
    {
        const int i  = threadIdx.x;
        const int oq = i >> 3;
        const int d0 = (i & 7) * 4;
        float sl = red[oq*RROW + 32].x + red[(32 + oq)*RROW + 32].x;
        float inv = 1.0f / sl;
        float2* o2 = (float2*)out;
        #pragma unroll
        for (int dd = 0; dd < 4; ++dd) {
            int d = d0 + dd;
            float2 v0 = red[oq*RROW + d];
            float2 v1 = red[(32 + oq)*RROW + d];
            o2[(size_t)(q0 + oq)*C_DIM + h*HD + d] =
                make_float2((v0.x + v1.x)*inv, (v0.y + v1.y)*inv);
        }
    }
}

extern "C" void kernel_launch(void* const* d_in, const int* in_sizes, int n_in,
                              void* d_out, int out_size, void* d_ws, size_t ws_size,
                              hipStream_t stream)
{
    const float* Q  = (const float*)d_in[0];
    const float* V  = (const float*)d_in[1];
    const float* K  = (const float*)d_in[2];
    const float* Wq = (const float*)d_in[3];
    const float* bq = (const float*)d_in[4];
    const float* Wk = (const float*)d_in[5];
    const float* bk = (const float*)d_in[6];
    const float* Wv = (const float*)d_in[7];
    const float* bv = (const float*)d_in[8];
    unsigned short* ws = (unsigned short*)d_ws;   // 6 planes * 2MB = 12MB
    float* out = (float*)d_out;

    dim3 gp(S_LEN/64, C_DIM/64, 3);
    proj_mfma<<<gp, 256, 0, stream>>>(Q, V, K, Wq, bq, Wk, bk, Wv, bv, ws);

    attn_mfma<<<dim3(64*NH), 256, 0, stream>>>(ws, out);
}

// Round 14
// 94.145 us; speedup vs baseline: 1.0203x; 1.0203x over previous
//
#include <hip/hip_runtime.h>
#include <hip/hip_bf16.h>
#include <math.h>

#define S_LEN 2048
#define C_DIM 512
#define NH 16
#define HD 32
#define PLANE_U (NH * S_LEN * HD)   // 1,048,576 ushorts = 2MB per plane

typedef __attribute__((ext_vector_type(8)))  short bf16x8;
typedef __attribute__((ext_vector_type(8)))  unsigned short u16x8;
typedef __attribute__((ext_vector_type(4)))  float f32x4;
typedef __attribute__((ext_vector_type(16))) float f32x16;
typedef __attribute__((ext_vector_type(4)))  unsigned int u32x4;

#if __has_builtin(__builtin_amdgcn_exp2f)
#define EXP2(x) __builtin_amdgcn_exp2f(x)
#else
#define EXP2(x) exp2f(x)
#endif

// pack 2 floats -> 2 bf16 in one dword via v_cvt_pk_bf16_f32 (RNE); a = low
__device__ __forceinline__ unsigned int pk_bf16(float a, float b) {
    float2 f; f.x = a; f.y = b;
    __hip_bfloat162 t = __float22bfloat162_rn(f);
    return *reinterpret_cast<unsigned int*>(&t);
}

// ---------------- projection: complex GEMM via bf16 MFMA ------------------
// A-operand (16 wave-private rows) loaded directly from global, converted
// in-register; only the shared B tile staged in LDS.
// z<2 (q,k): hi/lo split (12 mfma/chunk), D = W·X^T -> [h][s][d]; Q plane
//            PRE-SCALED by log2(e)/sqrt(32) (softmax exp2 folding).
// z==2 (v):  hi-only RNE, D = X·W^T -> CHUNK-INTERLEAVED V^T:
//            VT[h][s/32][d][{re,im}][32] -- for each (d, 32-key group) both
//            planes of 32 keys occupy ONE 128B line (attn reads 4 fragments
//            from a single line per group).
#define PROW 40   // padded LDS row stride in ushorts (80B, 16B-aligned)

__global__ __launch_bounds__(256)
void proj_mfma(const float* __restrict__ Q, const float* __restrict__ V,
               const float* __restrict__ K,
               const float* __restrict__ Wq, const float* __restrict__ bq,
               const float* __restrict__ Wk, const float* __restrict__ bk,
               const float* __restrict__ Wv, const float* __restrict__ bv,
               unsigned short* __restrict__ ws)
{
    const int z = blockIdx.z;
    const float *X, *W, *b;
    if (z == 0)      { X = Q; W = Wq; b = bq; }
    else if (z == 1) { X = K; W = Wk; b = bk; }
    else             { X = V; W = Wv; b = bv; }
    const bool full = (z < 2);

    const int s0 = blockIdx.x * 64;
    const int o0 = blockIdx.y * 64;

    const float2 *Asrc, *Bsrc; int arow0, brow0;
    if (full) { Asrc = (const float2*)W; arow0 = o0; Bsrc = (const float2*)X; brow0 = s0; }
    else      { Asrc = (const float2*)X; arow0 = s0; Bsrc = (const float2*)W; brow0 = o0; }

    __shared__ __align__(16) unsigned short LBrh[64*PROW], LBrl[64*PROW];
    __shared__ __align__(16) unsigned short LBih[64*PROW], LBil[64*PROW];

    const int t    = threadIdx.x;
    const int wave = t >> 6;
    const int lr   = t & 15;
    const int g    = (t & 63) >> 4;
    const int srow = t >> 2;        // B staging row 0..63
    const int sk8  = (t & 3) * 8;   // B staging k chunk (8 complex)

    const f32x4 zf = {0.f,0.f,0.f,0.f};
    f32x4 accR[4], accI[4];
    #pragma unroll
    for (int i = 0; i < 4; ++i) { accR[i] = zf; accI[i] = zf; }

    // per-lane A row (wave-private) — direct global loads each k-step
    const float4* Arow4 = (const float4*)(Asrc + (size_t)(arow0 + wave*16 + lr)*C_DIM);

    for (int k0 = 0; k0 < C_DIM; k0 += 32) {
        // issue A-fragment global load early (overlaps barrier + B staging)
        const float4* a4 = Arow4 + ((k0 + g*8) >> 1);   // 8 complex = 4 float4
        float4 A0 = a4[0], A1 = a4[1], A2 = a4[2], A3 = a4[3];

        __syncthreads();   // previous B tile fully consumed
        // ---- stage B tile (shared across waves) ----
        {
            const float4* s4 = (const float4*)(Bsrc + (size_t)(brow0 + srow)*C_DIM + k0 + sk8);
            float4 f0 = s4[0], f1 = s4[1], f2v = s4[2], f3 = s4[3];
            float re[8] = {f0.x,f0.z,f1.x,f1.z,f2v.x,f2v.z,f3.x,f3.z};
            float im[8] = {f0.y,f0.w,f1.y,f1.w,f2v.y,f2v.w,f3.y,f3.w};
            u32x4 rh, ih, rl, il;
            if (full) {
                #pragma unroll
                for (int p2 = 0; p2 < 4; ++p2) {
                    float r0f = re[2*p2], r1f = re[2*p2+1];
                    float i0f = im[2*p2], i1f = im[2*p2+1];
                    unsigned int br0 = __float_as_uint(r0f), br1 = __float_as_uint(r1f);
                    unsigned int bi0 = __float_as_uint(i0f), bi1 = __float_as_uint(i1f);
                    rh[p2] = __builtin_amdgcn_perm(br1, br0, 0x07060302u);  // [hi16(r1):hi16(r0)]
                    ih[p2] = __builtin_amdgcn_perm(bi1, bi0, 0x07060302u);
                    rl[p2] = pk_bf16(r0f - __uint_as_float(br0 & 0xFFFF0000u),
                                     r1f - __uint_as_float(br1 & 0xFFFF0000u));
                    il[p2] = pk_bf16(i0f - __uint_as_float(bi0 & 0xFFFF0000u),
                                     i1f - __uint_as_float(bi1 & 0xFFFF0000u));
                }
            } else {
                #pragma unroll
                for (int p2 = 0; p2 < 4; ++p2) {
                    rh[p2] = pk_bf16(re[2*p2], re[2*p2+1]);
                    ih[p2] = pk_bf16(im[2*p2], im[2*p2+1]);
                }
            }
            int wb = srow*PROW + sk8;
            *(u32x4*)&LBrh[wb] = rh; *(u32x4*)&LBih[wb] = ih;
            if (full) { *(u32x4*)&LBrl[wb] = rl; *(u32x4*)&LBil[wb] = il; }
        }

        // ---- convert A fragment in-register (while B stores land) ----
        bf16x8 aRH, aIH, aRL, aIL;
        {
            float re[8] = {A0.x,A0.z,A1.x,A1.z,A2.x,A2.z,A3.x,A3.z};
            float im[8] = {A0.y,A0.w,A1.y,A1.w,A2.y,A2.w,A3.y,A3.w};
            u32x4 rh, ih, rl, il;
            if (full) {
                #pragma unroll
                for (int p2 = 0; p2 < 4; ++p2) {
                    float r0f = re[2*p2], r1f = re[2*p2+1];
                    float i0f = im[2*p2], i1f = im[2*p2+1];
                    unsigned int br0 = __float_as_uint(r0f), br1 = __float_as_uint(r1f);
                    unsigned int bi0 = __float_as_uint(i0f), bi1 = __float_as_uint(i1f);
                    rh[p2] = __builtin_amdgcn_perm(br1, br0, 0x07060302u);
                    ih[p2] = __builtin_amdgcn_perm(bi1, bi0, 0x07060302u);
                    rl[p2] = pk_bf16(r0f - __uint_as_float(br0 & 0xFFFF0000u),
                                     r1f - __uint_as_float(br1 & 0xFFFF0000u));
                    il[p2] = pk_bf16(i0f - __uint_as_float(bi0 & 0xFFFF0000u),
                                     i1f - __uint_as_float(bi1 & 0xFFFF0000u));
                }
                aRL = *(bf16x8*)&rl; aIL = *(bf16x8*)&il;
            } else {
                #pragma unroll
                for (int p2 = 0; p2 < 4; ++p2) {
                    rh[p2] = pk_bf16(re[2*p2], re[2*p2+1]);
                    ih[p2] = pk_bf16(im[2*p2], im[2*p2+1]);
                }
            }
            aRH = *(bf16x8*)&rh; aIH = *(bf16x8*)&ih;
        }
        bf16x8 aIHn;
        #pragma unroll
        for (int j = 0; j < 8; ++j) aIHn[j] = aIH[j] ^ (short)0x8000;

        __syncthreads();   // B tile visible

        if (full) {
            bf16x8 aILn;
            #pragma unroll
            for (int j = 0; j < 8; ++j) aILn[j] = aIL[j] ^ (short)0x8000;

            #pragma unroll
            for (int tile = 0; tile < 4; ++tile) {
                const int bb = (tile*16 + lr)*PROW + g*8;
                bf16x8 bRH = *(const bf16x8*)&LBrh[bb];
                bf16x8 bRL = *(const bf16x8*)&LBrl[bb];
                bf16x8 bIH = *(const bf16x8*)&LBih[bb];
                bf16x8 bIL = *(const bf16x8*)&LBil[bb];
                accR[tile] = __builtin_amdgcn_mfma_f32_16x16x32_bf16(aRH,  bRH, accR[tile], 0,0,0);
                accR[tile] = __builtin_amdgcn_mfma_f32_16x16x32_bf16(aRL,  bRH, accR[tile], 0,0,0);
                accR[tile] = __builtin_amdgcn_mfma_f32_16x16x32_bf16(aRH,  bRL, accR[tile], 0,0,0);
                accR[tile] = __builtin_amdgcn_mfma_f32_16x16x32_bf16(aIHn, bIH, accR[tile], 0,0,0);
                accR[tile] = __builtin_amdgcn_mfma_f32_16x16x32_bf16(aILn, bIH, accR[tile], 0,0,0);
                accR[tile] = __builtin_amdgcn_mfma_f32_16x16x32_bf16(aIHn, bIL, accR[tile], 0,0,0);
                accI[tile] = __builtin_amdgcn_mfma_f32_16x16x32_bf16(aRH,  bIH, accI[tile], 0,0,0);
                accI[tile] = __builtin_amdgcn_mfma_f32_16x16x32_bf16(aRL,  bIH, accI[tile], 0,0,0);
                accI[tile] = __builtin_amdgcn_mfma_f32_16x16x32_bf16(aRH,  bIL, accI[tile], 0,0,0);
                accI[tile] = __builtin_amdgcn_mfma_f32_16x16x32_bf16(aIH,  bRH, accI[tile], 0,0,0);
                accI[tile] = __builtin_amdgcn_mfma_f32_16x16x32_bf16(aIL,  bRH, accI[tile], 0,0,0);
                accI[tile] = __builtin_amdgcn_mfma_f32_16x16x32_bf16(aIH,  bRL, accI[tile], 0,0,0);
            }
        } else {
            #pragma unroll
            for (int tile = 0; tile < 4; ++tile) {
                const int bb = (tile*16 + lr)*PROW + g*8;
                bf16x8 bRH = *(const bf16x8*)&LBrh[bb];
                bf16x8 bIH = *(const bf16x8*)&LBih[bb];
                accR[tile] = __builtin_amdgcn_mfma_f32_16x16x32_bf16(aRH,  bRH, accR[tile], 0,0,0);
                accR[tile] = __builtin_amdgcn_mfma_f32_16x16x32_bf16(aIHn, bIH, accR[tile], 0,0,0);
                accI[tile] = __builtin_amdgcn_mfma_f32_16x16x32_bf16(aRH,  bIH, accI[tile], 0,0,0);
                accI[tile] = __builtin_amdgcn_mfma_f32_16x16x32_bf16(aIH,  bRH, accI[tile], 0,0,0);
            }
        }
    }

    // ---- epilogue ----
    const float2* b2 = (const float2*)b;
    if (full) {
        // Q plane pre-scaled by log2(e)/sqrt(32): softmax uses exp2 directly
        const float osc = (z == 0) ? 0.2550348677f : 1.0f;
        unsigned short* pr = ws + (z == 0 ? 0 : 2) * (size_t)PLANE_U;
        unsigned short* pi = pr + PLANE_U;
        const int obase = o0 + wave*16 + g*4;
        const int h = obase >> 5, d0 = obase & 31;
        float bR[4], bI[4];
        #pragma unroll
        for (int r = 0; r < 4; ++r) { float2 bb = b2[obase + r]; bR[r] = bb.x; bI[r] = bb.y; }
        #pragma unroll
        for (int tile = 0; tile < 4; ++tile) {
            int s = s0 + tile*16 + lr;
            size_t idx = ((size_t)h*S_LEN + s)*HD + d0;
            uint2 pkR, pkI;
            pkR.x = pk_bf16((accR[tile][0]+bR[0])*osc, (accR[tile][1]+bR[1])*osc);
            pkR.y = pk_bf16((accR[tile][2]+bR[2])*osc, (accR[tile][3]+bR[3])*osc);
            pkI.x = pk_bf16((accI[tile][0]+bI[0])*osc, (accI[tile][1]+bI[1])*osc);
            pkI.y = pk_bf16((accI[tile][2]+bI[2])*osc, (accI[tile][3]+bI[3])*osc);
            *(uint2*)&pr[idx] = pkR;
            *(uint2*)&pi[idx] = pkI;
        }
    } else {
        // chunk-interleaved V^T: VT[h][c][d][{re,im}][32], c = s>>5
        unsigned short* vt = ws + 4 * (size_t)PLANE_U;
        const int sbase = s0 + wave*16 + g*4;
        const int c  = sbase >> 5;
        const int j0 = sbase & 31;
        #pragma unroll
        for (int tile = 0; tile < 4; ++tile) {
            int o = o0 + tile*16 + lr;
            int h = o >> 5, d = o & 31;
            float2 bb = b2[o];
            size_t base = ((((size_t)h*64 + c)*32 + d) << 6) + j0;
            uint2 pkR, pkI;
            pkR.x = pk_bf16(accR[tile][0]+bb.x, accR[tile][1]+bb.x);
            pkR.y = pk_bf16(accR[tile][2]+bb.x, accR[tile][3]+bb.x);
            pkI.x = pk_bf16(accI[tile][0]+bb.y, accI[tile][1]+bb.y);
            pkI.y = pk_bf16(accI[tile][2]+bb.y, accI[tile][3]+bb.y);
            *(uint2*)&vt[base]      = pkR;
            *(uint2*)&vt[base + 32] = pkI;
        }
    }
}

// ---------------- MFMA flash attention: 32x32x16, split-K 4 --------------
// One 32x32x16 covers all 32 q-rows. QK^T: S = mfma(K, Q) with the
// KEY->A-row permutation kappa(row) so D-reg r of lane-half b holds key
// {8b+r} (r<8) / {16+8b+r-8} -> P packs DIRECTLY into the PV B-fragment.
// PV: O^T = mfma(VT, P) with VT chunk-interleaved [h][k/32][d][{r,i}][32]:
// all 4 V fragments of a 32-key group come from ONE 128B line per d-row
// (4x less L1/L2 line traffic than the strided [h][d][s] layout).
// Softmax: p = exp2(|s'|), Q pre-scaled by log2(e)/sqrt(32). V loads are
// hoisted ABOVE the QK chain so their latency hides under it. 4 waves/block
// (256 thr) x split-K 4. Partials purely additive (no max tracking).
// Combine: two-stage into [2][32][33] float2 (conflict-free).
#define RROW 33

__global__ __launch_bounds__(256, 4)
void attn_mfma(const unsigned short* __restrict__ ws, float* __restrict__ out)
{
    const int bid   = blockIdx.x;       // 64 q-blocks x 16 heads
    const int h     = bid & (NH - 1);   // bid%8 = head%8 -> per-XCD KV locality
    const int qblk  = bid >> 4;         // 0..63
    const int wave  = threadIdx.x >> 6; // 0..3 -> k-range owner
    const int l     = threadIdx.x & 63;
    const int q     = l & 31;           // q-col AND VT d-row AND PV q-col
    const int b     = l >> 5;           // lane half

    const unsigned short* qr = ws + 0*(size_t)PLANE_U + (size_t)h*S_LEN*HD;
    const unsigned short* qi = ws + 1*(size_t)PLANE_U + (size_t)h*S_LEN*HD;
    const unsigned short* kr = ws + 2*(size_t)PLANE_U + (size_t)h*S_LEN*HD;
    const unsigned short* ki = ws + 3*(size_t)PLANE_U + (size_t)h*S_LEN*HD;
    const unsigned short* vt = ws + 4*(size_t)PLANE_U + ((size_t)h << 17); // 64*32*64

    const int q0 = qblk * 32;

    // key -> A-row permutation (see header comment); fixed per lane
    const int row   = q;
    const int kappa = (row & 16) + (((row >> 2) & 1) << 3) + (row & 3)
                    + (((row >> 3) & 1) << 2);

    // Q fragments (B-operand): lane supplies Q[q][d = b*8+j] (lo) / +16 (hi)
    bf16x8 bQr_lo = *(const bf16x8*)&qr[(size_t)(q0 + q)*HD + b*8];
    bf16x8 bQr_hi = *(const bf16x8*)&qr[(size_t)(q0 + q)*HD + 16 + b*8];
    bf16x8 bQi_lo = *(const bf16x8*)&qi[(size_t)(q0 + q)*HD + b*8];
    bf16x8 bQi_hi = *(const bf16x8*)&qi[(size_t)(q0 + q)*HD + 16 + b*8];

    // LDS only for the end-of-kernel two-stage combine: [2][32][33] float2
    __shared__ __align__(16) float2 red[2*32*RROW];

    f32x16 accR, accI;
    #pragma unroll
    for (int r = 0; r < 16; ++r) { accR[r] = 0.f; accI[r] = 0.f; }
    float lsum = 0.f;

    const f32x16 z16 = {0,0,0,0,0,0,0,0,0,0,0,0,0,0,0,0};
    const int kbeg = wave * 512;
    for (int k0 = kbeg; k0 < kbeg + 512; k0 += 32) {
        // ---- V fragments FIRST (one 128B line per d-row; latency hides
        //      under the QK chain) ----
        const size_t vbase = (((size_t)(k0 >> 5)*32 + q) << 6) + b*8;
        bf16x8 aVr_lo = *(const bf16x8*)&vt[vbase];
        bf16x8 aVr_hi = *(const bf16x8*)&vt[vbase + 16];
        bf16x8 aVi_lo = *(const bf16x8*)&vt[vbase + 32];
        bf16x8 aVi_hi = *(const bf16x8*)&vt[vbase + 48];

        // ---- K fragments: A[row][k] with permuted key rows ----
        const size_t krow = (size_t)(k0 + kappa)*HD + b*8;
        bf16x8 aKr_lo = *(const bf16x8*)&kr[krow];
        bf16x8 aKr_hi = *(const bf16x8*)&kr[krow + 16];
        bf16x8 aKi_lo = *(const bf16x8*)&ki[krow];
        bf16x8 aKi_hi = *(const bf16x8*)&ki[krow + 16];
        bf16x8 aKin_lo, aKin_hi;    // -Ki (transient)
        #pragma unroll
        for (int j = 0; j < 4; ++j) {
            ((unsigned int*)&aKin_lo)[j] = ((const unsigned int*)&aKi_lo)[j] ^ 0x80008000u;
            ((unsigned int*)&aKin_hi)[j] = ((const unsigned int*)&aKi_hi)[j] ^ 0x80008000u;
        }
        // ---- QK^T: 8 mfma, two independent 4-chains ----
        f32x16 sR = __builtin_amdgcn_mfma_f32_32x32x16_bf16(aKr_lo,  bQr_lo, z16, 0, 0, 0);
        f32x16 sI = __builtin_amdgcn_mfma_f32_32x32x16_bf16(aKin_lo, bQr_lo, z16, 0, 0, 0);
        sR = __builtin_amdgcn_mfma_f32_32x32x16_bf16(aKr_hi,  bQr_hi, sR, 0, 0, 0);
        sI = __builtin_amdgcn_mfma_f32_32x32x16_bf16(aKin_hi, bQr_hi, sI, 0, 0, 0);
        sR = __builtin_amdgcn_mfma_f32_32x32x16_bf16(aKi_lo,  bQi_lo, sR, 0, 0, 0);
        sI = __builtin_amdgcn_mfma_f32_32x32x16_bf16(aKr_lo,  bQi_lo, sI, 0, 0, 0);
        sR = __builtin_amdgcn_mfma_f32_32x32x16_bf16(aKi_hi,  bQi_hi, sR, 0, 0, 0);
        sI = __builtin_amdgcn_mfma_f32_32x32x16_bf16(aKr_hi,  bQi_hi, sI, 0, 0, 0);
        // ---- softmax: p[r] lands exactly in PV B-frag order ----
        bf16x8 bP1, bP2;
        unsigned int* p1 = (unsigned int*)&bP1;
        unsigned int* p2 = (unsigned int*)&bP2;
        #pragma unroll
        for (int r2 = 0; r2 < 8; ++r2) {
            int r = 2*r2;
            float v0 = EXP2(__builtin_amdgcn_sqrtf(fmaf(sR[r],   sR[r],   sI[r]*sI[r])));
            float v1 = EXP2(__builtin_amdgcn_sqrtf(fmaf(sR[r+1], sR[r+1], sI[r+1]*sI[r+1])));
            lsum += v0 + v1;
            if (r2 < 4) p1[r2]     = pk_bf16(v0, v1);
            else        p2[r2 - 4] = pk_bf16(v0, v1);
        }
        // ---- PV: A = VT (one line), B = P in-register ----
        accR = __builtin_amdgcn_mfma_f32_32x32x16_bf16(aVr_lo, bP1, accR, 0, 0, 0);
        accI = __builtin_amdgcn_mfma_f32_32x32x16_bf16(aVi_lo, bP1, accI, 0, 0, 0);
        accR = __builtin_amdgcn_mfma_f32_32x32x16_bf16(aVr_hi, bP2, accR, 0, 0, 0);
        accI = __builtin_amdgcn_mfma_f32_32x32x16_bf16(aVi_hi, bP2, accI, 0, 0, 0);
    }

    // lane pair (l, l^32) handled complementary key halves of the same q
    lsum += __shfl_xor(lsum, 32);

    // ---- two-stage combine: waves 0,1 write; 2,3 add; all reduce ----
    const int rrow = ((wave & 1) * 32 + q) * RROW;
    __syncthreads();
    if (wave < 2) {
        #pragma unroll
        for (int r = 0; r < 16; ++r) {
            int d = (r & 3) + 8*(r >> 2) + 4*b;   // PV D row = output d
            red[rrow + d] = make_float2(accR[r], accI[r]);
        }
        if (b == 0) red[rrow + 32].x = lsum;
    }
    __syncthreads();
    if (wave >= 2) {
        #pragma unroll
        for (int r = 0; r < 16; ++r) {
            int d = (r & 3) + 8*(r >> 2) + 4*b;
            float2 v = red[rrow + d];
            v.x += accR[r]; v.y += accI[r];
            red[rrow + d] = v;
        }
        if (b == 0) red[rrow + 32].x += lsum;
    }
    __syncthreads();

    // thread i: q-row = i>>3, d = (i&7)*4 .. +3 ; sum 2 stage-partials
    {
        const int i  = threadIdx.x;
        const int oq = i >> 3;
        const int d0 = (i & 7) * 4;
        float sl = red[oq*RROW + 32].x + red[(32 + oq)*RROW + 32].x;
        float inv = 1.0f / sl;
        float2* o2 = (float2*)out;
        #pragma unroll
        for (int dd = 0; dd < 4; ++dd) {
            int d = d0 + dd;
            float2 v0 = red[oq*RROW + d];
            float2 v1 = red[(32 + oq)*RROW + d];
            o2[(size_t)(q0 + oq)*C_DIM + h*HD + d] =
                make_float2((v0.x + v1.x)*inv, (v0.y + v1.y)*inv);
        }
    }
}

extern "C" void kernel_launch(void* const* d_in, const int* in_sizes, int n_in,
                              void* d_out, int out_size, void* d_ws, size_t ws_size,
                              hipStream_t stream)
{
    const float* Q  = (const float*)d_in[0];
    const float* V  = (const float*)d_in[1];
    const float* K  = (const float*)d_in[2];
    const float* Wq = (const float*)d_in[3];
    const float* bq = (const float*)d_in[4];
    const float* Wk = (const float*)d_in[5];
    const float* bk = (const float*)d_in[6];
    const float* Wv = (const float*)d_in[7];
    const float* bv = (const float*)d_in[8];
    unsigned short* ws = (unsigned short*)d_ws;   // 4 qk planes + 2MB*2 VT = 12MB
    float* out = (float*)d_out;

    dim3 gp(S_LEN/64, C_DIM/64, 3);
    proj_mfma<<<gp, 256, 0, stream>>>(Q, V, K, Wq, bq, Wk, bk, Wv, bv, ws);

    attn_mfma<<<dim3(64*NH), 256, 0, stream>>>(ws, out);
}